// Round 13
// baseline (359.672 us; speedup 1.0000x reference)
//
#include <hip/hip_runtime.h>
#include <hip/hip_cooperative_groups.h>
#include <cstddef>
#include <cstdint>

namespace cg = cooperative_groups;

namespace {
constexpr int kB   = 8;
constexpr int kT   = 2048;   // Tv == Ta
constexpr int kD   = 256;
constexpr int kK   = 8;      // num_neighbors (fixed by problem)
constexpr int kM   = kB * kT;
constexpr int kNCH = 64;     // s-chunks for gather partials (fallback path)
constexpr int kNC  = kB * kT;     // 16384 columns (b,s)
constexpr int kColCap = 64;       // bucket slots per column (mean load ~0.55)
constexpr int kOvCap  = 1 << 17;  // overflow list (normally empty)
constexpr int kStr = 264;         // LDS row stride in shorts (0 conflicts, r9-r11)
constexpr float kMinNormalF = 1.17549435e-38f;  // 2^-126: fp32 exp flush boundary
}

typedef __attribute__((ext_vector_type(8)))  __bf16 bf16x8;
typedef __attribute__((ext_vector_type(16))) float  f32x16;

__device__ inline unsigned short f2bf_rne(float x) {
  unsigned u = __float_as_uint(x);
  unsigned r = (u + 0x7FFFu + ((u >> 16) & 1u)) >> 16;
  return (unsigned short)r;
}
__device__ inline float bf2f(unsigned short h) {
  return __uint_as_float((unsigned)h << 16);
}
union FragU { uint4 u4; bf16x8 v; };

// ============================================================================
// Cooperative mega-kernel (grid-stride phases, works for any grid >= 64).
// r12 failed because grid=1024 was asserted, not queried; host now sizes the
// grid from hipOccupancyMaxActiveBlocksPerMultiprocessor and falls back to the
// r11 multi-kernel pipeline if the cooperative launch errors.
// ============================================================================
__global__ __launch_bounds__(256, 2) void mega(const float* __restrict__ visual,
                                               const float* __restrict__ audio,
                                               const float* __restrict__ Wv,
                                               const float* __restrict__ Wa,
                                               float* __restrict__ out,
                                               char* __restrict__ ws) {
  unsigned short* WvT = (unsigned short*)ws;
  unsigned short* WaT = WvT + (size_t)kD * kD;
  unsigned short* vmb = WaT + (size_t)kD * kD;
  unsigned short* amb = vmb + (size_t)kM * kD;
  float* vn2 = (float*)(amb + (size_t)kM * kD);
  float* an2 = vn2 + kM;
  unsigned* colCount = (unsigned*)(an2 + kM);
  unsigned* ovCount  = colCount + kNC;
  uint2* colRecs = (uint2*)(ovCount + 8);
  uint2* ovRecs  = colRecs + (size_t)kNC * kColCap;
  float* pv = (float*)(ovRecs + kOvCap);
  float* pa = pv + (size_t)4096 * kD;

  __shared__ unsigned short S[64 * kStr];                   // 33792 B
  cg::grid_group grid = cg::this_grid();
  const int G = gridDim.x;
  const int blk = blockIdx.x;
  const int tid = threadIdx.x;
  const int w = tid >> 6, lane = tid & 63;
  const int half = lane >> 5, ln = lane & 31;

  // ===== phase 0: W transpose (grid-stride over 128 tiles) + zero scratch ===
  for (int t = blk; t < 128; t += G) {
    __syncthreads();
    const float* W = (t & 64) ? Wa : Wv;
    unsigned short* WT = (t & 64) ? WaT : WvT;
    const int tt = t & 63;
    const int c0 = (tt & 7) * 32, k0 = (tt >> 3) * 32;
    float* tile = (float*)S;  // [32][33] overlay
    const int tx = tid & 31, ty = tid >> 5;
#pragma unroll
    for (int i = 0; i < 4; ++i)
      tile[(ty + i * 8) * 33 + tx] = W[(size_t)(k0 + ty + i * 8) * kD + c0 + tx];
    __syncthreads();
#pragma unroll
    for (int i = 0; i < 4; ++i)
      WT[(size_t)(c0 + ty + i * 8) * kD + k0 + tx] = f2bf_rne(tile[tx * 33 + ty + i * 8]);
  }
  {
    unsigned* zb = (unsigned*)vn2;
    const int zeroWords = 2 * kM + kNC + 8;
    for (int i = blk * 256 + tid; i < zeroWords; i += G * 256) zb[i] = 0u;
  }
  grid.sync();

  // ===== phase 1: gemm, 1024 tiles (r11 gemm_hyb body, grid-stride) =========
  for (int task = blk; task < 1024; task += G) {
    const int z = task >> 9;
    const int cHalf = (task >> 8) & 1;
    const int r0 = (task & 255) * 64;
    const float* X = z ? audio : visual;
    const unsigned short* WT = z ? WaT : WvT;
    unsigned short* Cb = z ? amb : vmb;
    float* nrm = z ? an2 : vn2;
    const int wt = w & 1, wc = w >> 1;

    __syncthreads();  // protect S from prior iteration/phase
#pragma unroll
    for (int i = 0; i < 16; ++i) {
      const int idx = i * 256 + tid;
      const int row = idx >> 6, g = idx & 63;
      const float4 v = *reinterpret_cast<const float4*>(X + (size_t)(r0 + row) * kD + g * 4);
      ushort4 o;
      o.x = f2bf_rne(v.x); o.y = f2bf_rne(v.y); o.z = f2bf_rne(v.z); o.w = f2bf_rne(v.w);
      *reinterpret_cast<ushort4*>(S + row * kStr + g * 4) = o;
    }
    __syncthreads();
    uint4 afr[16];
#pragma unroll
    for (int kc = 0; kc < 16; ++kc)
      afr[kc] = *reinterpret_cast<const uint4*>(S + (wt * 32 + ln) * kStr + kc * 16 + half * 8);

    float ns[16];
#pragma unroll
    for (int r = 0; r < 16; ++r) ns[r] = 0.0f;

    for (int ct = 0; ct < 2; ++ct) {
      const int c0 = (cHalf * 2 + ct) * 64;
      __syncthreads();  // afr reads / prev MFMA fb reads done
#pragma unroll
      for (int i = 0; i < 8; ++i) {
        const int idx = i * 256 + tid;
        const int row = idx >> 5, g = idx & 31;
        const uint4 v = *reinterpret_cast<const uint4*>(WT + (size_t)(c0 + row) * kD + g * 8);
        *reinterpret_cast<uint4*>(S + row * kStr + g * 8) = v;
      }
      __syncthreads();
      f32x16 acc;
#pragma unroll
      for (int i = 0; i < 16; ++i) acc[i] = 0.0f;
#pragma unroll
      for (int kc = 0; kc < 16; ++kc) {
        FragU fa, fb;
        fa.u4 = afr[kc];
        fb.u4 = *reinterpret_cast<const uint4*>(S + (wc * 32 + ln) * kStr + kc * 16 + half * 8);
        acc = __builtin_amdgcn_mfma_f32_32x32x16_bf16(fa.v, fb.v, acc, 0, 0, 0);
      }
      const int col = c0 + wc * 32 + ln;
#pragma unroll
      for (int r = 0; r < 16; ++r) {
        const int row = r0 + wt * 32 + (r & 3) + 8 * (r >> 2) + 4 * half;
        const unsigned short us = f2bf_rne(acc[r]);
        Cb[(size_t)row * kD + col] = us;
        const float f = bf2f(us);
        ns[r] += f * f;
      }
    }
#pragma unroll
    for (int r = 0; r < 16; ++r) {
      float v = ns[r];
#pragma unroll
      for (int off = 1; off < 32; off <<= 1) v += __shfl_xor(v, off, 64);
      if (ln == 0) {
        const int row = r0 + wt * 32 + (r & 3) + 8 * (r >> 2) + 4 * half;
        atomicAdd(nrm + row, v);
      }
    }
  }
  grid.sync();

  // ===== phase 2: keys, 1024 tiles (r11 keys_v12 body, grid-stride) =========
  for (int task = blk; task < 1024; task += G) {
    const int b = task >> 7;
    const int rem = task & 127;
    const int t0 = (rem >> 3) * 128;
    const int sr0 = (rem & 7) * 256;

    uint4 afr[16];
#pragma unroll
    for (int h = 0; h < 2; ++h) {
      __syncthreads();  // protect S from prior phase/iteration/half reads
#pragma unroll
      for (int i = 0; i < 8; ++i) {
        const int idx = i * 256 + tid;
        const int row = idx >> 5, g = idx & 31;
        const uint4 v = *reinterpret_cast<const uint4*>(
            vmb + ((size_t)b * kT + t0 + h * 64 + row) * kD + g * 8);
        *reinterpret_cast<uint4*>(S + row * kStr + g * 8) = v;
      }
      __syncthreads();
      if ((w >> 1) == h) {
#pragma unroll
        for (int kc = 0; kc < 16; ++kc)
          afr[kc] = *reinterpret_cast<const uint4*>(S + ((w & 1) * 32 + ln) * kStr + kc * 16 + half * 8);
      }
    }

    const float* v2p = vn2 + (size_t)b * kT + t0 + w * 32;

    for (int st = 0; st < 4; ++st) {
      const int s0 = sr0 + st * 64;
      __syncthreads();  // afr reads / prev MFMA fb reads done
#pragma unroll
      for (int i = 0; i < 8; ++i) {
        const int idx = i * 256 + tid;
        const int row = idx >> 5, g = idx & 31;
        const uint4 v = *reinterpret_cast<const uint4*>(
            amb + ((size_t)b * kT + s0 + row) * kD + g * 8);
        *reinterpret_cast<uint4*>(S + row * kStr + g * 8) = v;
      }
      __syncthreads();
      f32x16 acc[2];
#pragma unroll
      for (int j = 0; j < 2; ++j)
#pragma unroll
        for (int i = 0; i < 16; ++i) acc[j][i] = 0.0f;
#pragma unroll
      for (int kc = 0; kc < 16; ++kc) {
        FragU fa; fa.u4 = afr[kc];
#pragma unroll
        for (int ss = 0; ss < 2; ++ss) {
          FragU fb;
          fb.u4 = *reinterpret_cast<const uint4*>(S + (ss * 32 + ln) * kStr + kc * 16 + half * 8);
          acc[ss] = __builtin_amdgcn_mfma_f32_32x32x16_bf16(fa.v, fb.v, acc[ss], 0, 0, 0);
        }
      }
#pragma unroll
      for (int ss = 0; ss < 2; ++ss) {
        const int s = s0 + ss * 32 + ln;
        const float a2 = an2[(size_t)b * kT + s];
        const int c = (b << 11) | s;
#pragma unroll
        for (int g = 0; g < 4; ++g) {
          const float4 v2 = *reinterpret_cast<const float4*>(v2p + g * 8 + half * 4);
          const float v2a[4] = {v2.x, v2.y, v2.z, v2.w};
#pragma unroll
          for (int q = 0; q < 4; ++q) {
            const float raw = v2a[q] + a2 - 2.0f * acc[ss][4 * g + q];
            if (raw < 7744.0f) {  // == dist < 88; ~3e-4 of entries
              const float dist = sqrtf(fmaxf(raw, 0.0f));
              const float e = expf(-dist);
              if (e >= kMinNormalF) {
                const int t = t0 + w * 32 + g * 8 + half * 4 + q;
                const unsigned slot = atomicAdd(&colCount[c], 1u);
                if (slot < (unsigned)kColCap) {
                  colRecs[(size_t)c * kColCap + slot] = make_uint2(__float_as_uint(e), (unsigned)t);
                } else {
                  const unsigned pos = ((unsigned)b << 22) | ((unsigned)s << 11) | (unsigned)t;
                  const unsigned oi = atomicAdd(ovCount, 1u);
                  if (oi < (unsigned)kOvCap) ovRecs[oi] = make_uint2(__float_as_uint(e), pos);
                }
              }
            }
          }
        }
      }
    }
  }
  grid.sync();

  // ===== phase 3: per-column top-8 (fused finalize) + gather ================
  for (int u = blk; u < 4096; u += G) {
    const int bj = u >> 6, ch = u & 63;
    const int b = bj >> 3, j = bj & 7;
    int* sIdx = (int*)S;
    __syncthreads();  // protect S reuse
    if (tid < 32) {
      const int s = ch * 32 + tid;
      const int c = (b << 11) | s;
      unsigned K[8]; int T[8];
#pragma unroll
      for (int i = 0; i < 8; ++i) { K[i] = 0u; T[i] = 0x7FFFFFFF; }
      const int cnt = (int)colCount[c];
      const int m = min(cnt, kColCap);
      for (int i = 0; i < m; ++i) {
        const uint2 r = colRecs[(size_t)c * kColCap + i];
        const unsigned kx = r.x; const int tx = (int)r.y;
        if (kx > K[7] || (kx == K[7] && tx < T[7])) {
          K[7] = kx; T[7] = tx;
#pragma unroll
          for (int q = 7; q >= 1; --q) {
            const bool sw = (K[q] > K[q - 1]) || (K[q] == K[q - 1] && T[q] < T[q - 1]);
            if (sw) {
              const unsigned tk = K[q]; K[q] = K[q - 1]; K[q - 1] = tk;
              const int tt = T[q];      T[q] = T[q - 1]; T[q - 1] = tt;
            }
          }
        }
      }
      if (cnt > kColCap) {  // correctness fallback; normally never taken
        int n = (int)*ovCount;
        if (n > kOvCap) n = kOvCap;
        for (int i = 0; i < n; ++i) {
          const uint2 r = ovRecs[i];
          if ((int)(r.y >> 11) == c) {
            const unsigned kx = r.x; const int tx = (int)(r.y & 2047u);
            if (kx > K[7] || (kx == K[7] && tx < T[7])) {
              K[7] = kx; T[7] = tx;
#pragma unroll
              for (int q = 7; q >= 1; --q) {
                const bool sw = (K[q] > K[q - 1]) || (K[q] == K[q - 1] && T[q] < T[q - 1]);
                if (sw) {
                  const unsigned tk = K[q]; K[q] = K[q - 1]; K[q - 1] = tk;
                  const int tt = T[q];      T[q] = T[q - 1]; T[q - 1] = tt;
                }
              }
            }
          }
        }
      }
      int mcnt = 0;
#pragma unroll
      for (int i = 0; i < 8; ++i) if (K[i] > 0u) mcnt++;
      int outv[8];
#pragma unroll
      for (int i = 0; i < 8; ++i) outv[i] = T[i];
      int cand = 0;
      for (int r = mcnt; r < 8; ++r) {
        bool taken = true;
        while (taken) {
          taken = false;
#pragma unroll
          for (int q = 0; q < 8; ++q)
            if (q < mcnt && T[q] == cand) taken = true;
          if (taken) cand++;
        }
        outv[r] = cand++;
      }
      sIdx[tid] = outv[j];
    }
    __syncthreads();
    float accV = 0.f, accA = 0.f;
    for (int i = 0; i < 32; ++i) {
      const int t = sIdx[i];
      const size_t base = ((size_t)b * kT + t) * kD + tid;
      accV += visual[base];
      accA += audio[base];
    }
    pv[(size_t)u * kD + tid] = accV;
    pa[(size_t)u * kD + tid] = accA;
  }
  grid.sync();

  // ===== phase 4: reduce partials -> out ====================================
  for (int bj = blk; bj < kB * kK; bj += G) {
    float sV = 0.f, sA = 0.f;
#pragma unroll 8
    for (int ch = 0; ch < 64; ++ch) {
      sV += pv[((size_t)bj * 64 + ch) * kD + tid];
      sA += pa[((size_t)bj * 64 + ch) * kD + tid];
    }
    out[(size_t)bj * kD + tid] = sV * (1.0f / kT);
    out[(size_t)kB * kK * kD + (size_t)bj * kD + tid] = sA * (1.0f / kT);
  }
}

// ============================================================================
// Fallback pipeline — r11 kernels verbatim (known-good: 175.5us, absmax .0156)
// ============================================================================
__global__ __launch_bounds__(256) void prep(const float* __restrict__ W0,
                                            const float* __restrict__ W1,
                                            unsigned short* __restrict__ T0,
                                            unsigned short* __restrict__ T1,
                                            unsigned* __restrict__ zeroBase,
                                            int zeroWords) {
  const int blk = blockIdx.x;
  if (blk < 128) {
    const float* W = (blk & 64) ? W1 : W0;
    unsigned short* WT = (blk & 64) ? T1 : T0;
    const int t = blk & 63;
    const int c0 = (t & 7) * 32, k0 = (t >> 3) * 32;
    __shared__ float tile[32][33];
    const int tx = threadIdx.x & 31, ty = threadIdx.x >> 5;
#pragma unroll
    for (int i = 0; i < 4; ++i)
      tile[ty + i * 8][tx] = W[(size_t)(k0 + ty + i * 8) * kD + c0 + tx];
    __syncthreads();
#pragma unroll
    for (int i = 0; i < 4; ++i)
      WT[(size_t)(c0 + ty + i * 8) * kD + k0 + tx] = f2bf_rne(tile[tx][ty + i * 8]);
  } else {
    for (int i = (blk - 128) * 256 + threadIdx.x; i < zeroWords; i += 32 * 256)
      zeroBase[i] = 0u;
  }
}

__global__ __launch_bounds__(256) void gemm_hyb(const float* __restrict__ Xv,
                                                const float* __restrict__ Xa,
                                                const unsigned short* __restrict__ WvT,
                                                const unsigned short* __restrict__ WaT,
                                                unsigned short* __restrict__ Cv,
                                                unsigned short* __restrict__ Ca,
                                                float* __restrict__ nv,
                                                float* __restrict__ na) {
  __shared__ unsigned short S[64 * kStr];
  const int z = blockIdx.z;
  const float* X = z ? Xa : Xv;
  const unsigned short* WT = z ? WaT : WvT;
  unsigned short* Cb = z ? Ca : Cv;
  float* nrm = z ? na : nv;
  const int r0 = blockIdx.x * 64;
  const int cHalf = blockIdx.y;
  const int tid = threadIdx.x;
  const int w = tid >> 6, lane = tid & 63;
  const int wt = w & 1, wc = w >> 1;
  const int half = lane >> 5, ln = lane & 31;

#pragma unroll
  for (int i = 0; i < 16; ++i) {
    const int idx = i * 256 + tid;
    const int row = idx >> 6, g = idx & 63;
    const float4 v = *reinterpret_cast<const float4*>(X + (size_t)(r0 + row) * kD + g * 4);
    ushort4 o;
    o.x = f2bf_rne(v.x); o.y = f2bf_rne(v.y); o.z = f2bf_rne(v.z); o.w = f2bf_rne(v.w);
    *reinterpret_cast<ushort4*>(S + row * kStr + g * 4) = o;
  }
  __syncthreads();
  uint4 afr[16];
#pragma unroll
  for (int kc = 0; kc < 16; ++kc)
    afr[kc] = *reinterpret_cast<const uint4*>(S + (wt * 32 + ln) * kStr + kc * 16 + half * 8);

  float ns[16];
#pragma unroll
  for (int r = 0; r < 16; ++r) ns[r] = 0.0f;

  for (int ct = 0; ct < 2; ++ct) {
    const int c0 = (cHalf * 2 + ct) * 64;
    __syncthreads();
#pragma unroll
    for (int i = 0; i < 8; ++i) {
      const int idx = i * 256 + tid;
      const int row = idx >> 5, g = idx & 31;
      const uint4 v = *reinterpret_cast<const uint4*>(WT + (size_t)(c0 + row) * kD + g * 8);
      *reinterpret_cast<uint4*>(S + row * kStr + g * 8) = v;
    }
    __syncthreads();
    f32x16 acc;
#pragma unroll
    for (int i = 0; i < 16; ++i) acc[i] = 0.0f;
#pragma unroll
    for (int kc = 0; kc < 16; ++kc) {
      FragU fa, fb;
      fa.u4 = afr[kc];
      fb.u4 = *reinterpret_cast<const uint4*>(S + (wc * 32 + ln) * kStr + kc * 16 + half * 8);
      acc = __builtin_amdgcn_mfma_f32_32x32x16_bf16(fa.v, fb.v, acc, 0, 0, 0);
    }
    const int col = c0 + wc * 32 + ln;
#pragma unroll
    for (int r = 0; r < 16; ++r) {
      const int row = r0 + wt * 32 + (r & 3) + 8 * (r >> 2) + 4 * half;
      const unsigned short us = f2bf_rne(acc[r]);
      Cb[(size_t)row * kD + col] = us;
      const float f = bf2f(us);
      ns[r] += f * f;
    }
  }
#pragma unroll
  for (int r = 0; r < 16; ++r) {
    float v = ns[r];
#pragma unroll
    for (int off = 1; off < 32; off <<= 1) v += __shfl_xor(v, off, 64);
    if (ln == 0) {
      const int row = r0 + wt * 32 + (r & 3) + 8 * (r >> 2) + 4 * half;
      atomicAdd(nrm + row, v);
    }
  }
}

__global__ __launch_bounds__(256) void keys_v12(const unsigned short* __restrict__ vmb,
                                                const unsigned short* __restrict__ amb,
                                                const float* __restrict__ vn2,
                                                const float* __restrict__ an2,
                                                unsigned* __restrict__ colCount,
                                                uint2* __restrict__ colRecs,
                                                unsigned* __restrict__ ovCount,
                                                uint2* __restrict__ ovRecs) {
  __shared__ unsigned short S[64 * kStr];
  const int b = blockIdx.z;
  const int t0 = blockIdx.x * 128;
  const int sr0 = blockIdx.y * 256;
  const int tid = threadIdx.x;
  const int w = tid >> 6, lane = tid & 63;
  const int half = lane >> 5, ln = lane & 31;

  uint4 afr[16];
#pragma unroll
  for (int h = 0; h < 2; ++h) {
#pragma unroll
    for (int i = 0; i < 8; ++i) {
      const int idx = i * 256 + tid;
      const int row = idx >> 5, g = idx & 31;
      const uint4 v = *reinterpret_cast<const uint4*>(
          vmb + ((size_t)b * kT + t0 + h * 64 + row) * kD + g * 8);
      *reinterpret_cast<uint4*>(S + row * kStr + g * 8) = v;
    }
    __syncthreads();
    if ((w >> 1) == h) {
#pragma unroll
      for (int kc = 0; kc < 16; ++kc)
        afr[kc] = *reinterpret_cast<const uint4*>(S + ((w & 1) * 32 + ln) * kStr + kc * 16 + half * 8);
    }
    __syncthreads();
  }

  const float* v2p = vn2 + (size_t)b * kT + t0 + w * 32;

  for (int st = 0; st < 4; ++st) {
    const int s0 = sr0 + st * 64;
    if (st) __syncthreads();
#pragma unroll
    for (int i = 0; i < 8; ++i) {
      const int idx = i * 256 + tid;
      const int row = idx >> 5, g = idx & 31;
      const uint4 v = *reinterpret_cast<const uint4*>(
          amb + ((size_t)b * kT + s0 + row) * kD + g * 8);
      *reinterpret_cast<uint4*>(S + row * kStr + g * 8) = v;
    }
    __syncthreads();
    f32x16 acc[2];
#pragma unroll
    for (int j = 0; j < 2; ++j)
#pragma unroll
      for (int i = 0; i < 16; ++i) acc[j][i] = 0.0f;
#pragma unroll
    for (int kc = 0; kc < 16; ++kc) {
      FragU fa; fa.u4 = afr[kc];
#pragma unroll
      for (int ss = 0; ss < 2; ++ss) {
        FragU fb;
        fb.u4 = *reinterpret_cast<const uint4*>(S + (ss * 32 + ln) * kStr + kc * 16 + half * 8);
        acc[ss] = __builtin_amdgcn_mfma_f32_32x32x16_bf16(fa.v, fb.v, acc[ss], 0, 0, 0);
      }
    }
#pragma unroll
    for (int ss = 0; ss < 2; ++ss) {
      const int s = s0 + ss * 32 + ln;
      const float a2 = an2[(size_t)b * kT + s];
      const int c = (b << 11) | s;
#pragma unroll
      for (int g = 0; g < 4; ++g) {
        const float4 v2 = *reinterpret_cast<const float4*>(v2p + g * 8 + half * 4);
        const float v2a[4] = {v2.x, v2.y, v2.z, v2.w};
#pragma unroll
        for (int q = 0; q < 4; ++q) {
          const float raw = v2a[q] + a2 - 2.0f * acc[ss][4 * g + q];
          if (raw < 7744.0f) {
            const float dist = sqrtf(fmaxf(raw, 0.0f));
            const float e = expf(-dist);
            if (e >= kMinNormalF) {
              const int t = t0 + w * 32 + g * 8 + half * 4 + q;
              const unsigned slot = atomicAdd(&colCount[c], 1u);
              if (slot < (unsigned)kColCap) {
                colRecs[(size_t)c * kColCap + slot] = make_uint2(__float_as_uint(e), (unsigned)t);
              } else {
                const unsigned pos = ((unsigned)b << 22) | ((unsigned)s << 11) | (unsigned)t;
                const unsigned oi = atomicAdd(ovCount, 1u);
                if (oi < (unsigned)kOvCap) ovRecs[oi] = make_uint2(__float_as_uint(e), pos);
              }
            }
          }
        }
      }
    }
  }
}

__global__ __launch_bounds__(256) void finalize_topk(const unsigned* __restrict__ colCount,
                                                     const uint2* __restrict__ colRecs,
                                                     const unsigned* __restrict__ ovCount,
                                                     const uint2* __restrict__ ovRecs,
                                                     int* __restrict__ idxT) {
  const int c = blockIdx.x * 256 + threadIdx.x;
  unsigned K[8];
  int T[8];
#pragma unroll
  for (int i = 0; i < 8; ++i) { K[i] = 0u; T[i] = 0x7FFFFFFF; }
  const int cnt = (int)colCount[c];
  const int m = min(cnt, kColCap);
  for (int i = 0; i < m; ++i) {
    const uint2 r = colRecs[(size_t)c * kColCap + i];
    const unsigned kx = r.x;
    const int tx = (int)r.y;
    if (kx > K[7] || (kx == K[7] && tx < T[7])) {
      K[7] = kx; T[7] = tx;
#pragma unroll
      for (int q = 7; q >= 1; --q) {
        const bool sw = (K[q] > K[q - 1]) || (K[q] == K[q - 1] && T[q] < T[q - 1]);
        if (sw) {
          const unsigned tk = K[q]; K[q] = K[q - 1]; K[q - 1] = tk;
          const int tt = T[q];      T[q] = T[q - 1]; T[q - 1] = tt;
        }
      }
    }
  }
  if (cnt > kColCap) {
    int n = (int)*ovCount;
    if (n > kOvCap) n = kOvCap;
    for (int i = 0; i < n; ++i) {
      const uint2 r = ovRecs[i];
      if ((int)(r.y >> 11) == c) {
        const unsigned kx = r.x;
        const int tx = (int)(r.y & 2047u);
        if (kx > K[7] || (kx == K[7] && tx < T[7])) {
          K[7] = kx; T[7] = tx;
#pragma unroll
          for (int q = 7; q >= 1; --q) {
            const bool sw = (K[q] > K[q - 1]) || (K[q] == K[q - 1] && T[q] < T[q - 1]);
            if (sw) {
              const unsigned tk = K[q]; K[q] = K[q - 1]; K[q - 1] = tk;
              const int tt = T[q];      T[q] = T[q - 1]; T[q - 1] = tt;
            }
          }
        }
      }
    }
  }
  int mcnt = 0;
#pragma unroll
  for (int i = 0; i < 8; ++i) if (K[i] > 0u) mcnt++;
  int outv[8];
#pragma unroll
  for (int i = 0; i < 8; ++i) outv[i] = T[i];
  int cand = 0;
  for (int r = mcnt; r < 8; ++r) {
    bool taken = true;
    while (taken) {
      taken = false;
#pragma unroll
      for (int q = 0; q < 8; ++q)
        if (q < mcnt && T[q] == cand) taken = true;
      if (taken) cand++;
    }
    outv[r] = cand++;
  }
  const int b = c >> 11, s = c & 2047;
#pragma unroll
  for (int r = 0; r < 8; ++r) idxT[((size_t)b * kK + r) * kT + s] = outv[r];
}

__global__ __launch_bounds__(256) void gather_kernel(const float* __restrict__ visual,
                                                     const float* __restrict__ audio,
                                                     const int* __restrict__ idxT,
                                                     float* __restrict__ pv,
                                                     float* __restrict__ pa) {
  const int blk = blockIdx.x;
  const int ch = blk & (kNCH - 1);
  const int bj = blk / kNCH;
  const int b = bj >> 3;
  const int d = threadIdx.x;
  const int* ip = idxT + (size_t)bj * kT + ch * (kT / kNCH);
  float accV = 0.f, accA = 0.f;
  for (int g = 0; g < kT / kNCH / 4; ++g) {
    const int4 cur = *reinterpret_cast<const int4*>(ip + g * 4);
    const int ts[4] = {cur.x, cur.y, cur.z, cur.w};
#pragma unroll
    for (int u = 0; u < 4; ++u) {
      const size_t base = ((size_t)b * kT + ts[u]) * kD + d;
      accV += visual[base];
      accA += audio[base];
    }
  }
  pv[(size_t)blk * kD + d] = accV;
  pa[(size_t)blk * kD + d] = accA;
}

__global__ __launch_bounds__(256) void reduce_kernel(const float* __restrict__ pv,
                                                     const float* __restrict__ pa,
                                                     float* __restrict__ out) {
  const int bj = blockIdx.x;
  const int d = threadIdx.x;
  float sV = 0.f, sA = 0.f;
#pragma unroll 8
  for (int ch = 0; ch < kNCH; ++ch) {
    sV += pv[((size_t)bj * kNCH + ch) * kD + d];
    sA += pa[((size_t)bj * kNCH + ch) * kD + d];
  }
  out[(size_t)bj * kD + d] = sV * (1.0f / kT);
  out[(size_t)kB * kK * kD + (size_t)bj * kD + d] = sA * (1.0f / kT);
}

extern "C" void kernel_launch(void* const* d_in, const int* in_sizes, int n_in,
                              void* d_out, int out_size, void* d_ws, size_t ws_size,
                              hipStream_t stream) {
  (void)in_sizes; (void)n_in; (void)out_size; (void)ws_size;
  const float* visual = (const float*)d_in[0];
  const float* audio  = (const float*)d_in[1];
  const float* Wv     = (const float*)d_in[2];
  const float* Wa     = (const float*)d_in[3];
  float* out = (float*)d_out;
  char* wsc = (char*)d_ws;

  // shared workspace layout (coop + fallback)
  unsigned short* WvT = (unsigned short*)wsc;
  unsigned short* WaT = WvT + (size_t)kD * kD;
  unsigned short* vmb = WaT + (size_t)kD * kD;
  unsigned short* amb = vmb + (size_t)kM * kD;
  float* vn2 = (float*)(amb + (size_t)kM * kD);
  float* an2 = vn2 + kM;
  unsigned* colCount = (unsigned*)(an2 + kM);
  unsigned* ovCount  = colCount + kNC;
  uint2* colRecs = (uint2*)(ovCount + 8);
  uint2* ovRecs  = colRecs + (size_t)kNC * kColCap;
  float* pv = (float*)(ovRecs + kOvCap);
  float* pa = pv + (size_t)4096 * kD;
  int* idxT = (int*)(pa + (size_t)4096 * kD);   // fallback only
  const int zeroWords = 2 * kM + kNC + 8;

  // size the cooperative grid from the runtime's own occupancy answer
  int dev = 0;
  (void)hipGetDevice(&dev);
  int numCU = 0, maxPerCU = 0;
  (void)hipDeviceGetAttribute(&numCU, hipDeviceAttributeMultiprocessorCount, dev);
  hipError_t qerr = hipOccupancyMaxActiveBlocksPerMultiprocessor(&maxPerCU, mega, 256, 0);

  hipError_t lerr = hipErrorUnknown;
  if (qerr == hipSuccess && maxPerCU > 0 && numCU > 0) {
    int grid = maxPerCU * numCU;
    if (grid > 1024) grid = 1024;
    if (grid >= 64) {
      void* args[] = {(void*)&visual, (void*)&audio, (void*)&Wv, (void*)&Wa,
                      (void*)&out, (void*)&wsc};
      lerr = hipLaunchCooperativeKernel((const void*)mega, dim3(grid), dim3(256),
                                        args, 0, stream);
    }
  }
  if (lerr != hipSuccess) {
    (void)hipGetLastError();  // clear sticky error, run proven r11 pipeline
    prep<<<dim3(160), 256, 0, stream>>>(Wv, Wa, WvT, WaT, (unsigned*)vn2, zeroWords);
    gemm_hyb<<<dim3(kM / 64, 2, 2), 256, 0, stream>>>(visual, audio, WvT, WaT,
                                                      vmb, amb, vn2, an2);
    keys_v12<<<dim3(kT / 128, kT / 256, kB), 256, 0, stream>>>(vmb, amb, vn2, an2,
                                                               colCount, colRecs, ovCount, ovRecs);
    finalize_topk<<<dim3(kNC / 256), 256, 0, stream>>>(colCount, colRecs, ovCount, ovRecs, idxT);
    gather_kernel<<<dim3(kB * kK * kNCH), 256, 0, stream>>>(visual, audio, idxT, pv, pa);
    reduce_kernel<<<dim3(kB * kK), 256, 0, stream>>>(pv, pa, out);
  }
}

// Round 14
// 158.626 us; speedup vs baseline: 2.2674x; 2.2674x over previous
//
#include <hip/hip_runtime.h>
#include <cstddef>
#include <cstdint>

namespace {
constexpr int kB   = 8;
constexpr int kT   = 2048;   // Tv == Ta
constexpr int kD   = 256;
constexpr int kK   = 8;      // num_neighbors (fixed by problem)
constexpr int kM   = kB * kT;
constexpr int kNC  = kB * kT;     // 16384 columns (b,s)
constexpr int kColCap = 64;       // bucket slots per column (mean load ~0.55)
constexpr int kOvCap  = 1 << 17;  // overflow list (normally empty)
constexpr int kStr = 264;         // padded LDS stride (gemm X tile only)
constexpr float kMinNormalF = 1.17549435e-38f;  // 2^-126: fp32 exp flush boundary
}

typedef __attribute__((ext_vector_type(8)))  __bf16 bf16x8;
typedef __attribute__((ext_vector_type(16))) float  f32x16;

__device__ inline unsigned short f2bf_rne(float x) {
  unsigned u = __float_as_uint(x);
  unsigned r = (u + 0x7FFFu + ((u >> 16) & 1u)) >> 16;
  return (unsigned short)r;
}
__device__ inline float bf2f(unsigned short h) {
  return __uint_as_float((unsigned)h << 16);
}
union FragU { uint4 u4; bf16x8 v; };

// Async global->LDS, 16B per lane (m97's width=16 path). LDS dest is
// wave-uniform base + lane*16; global addr is per-lane.
__device__ inline void async16(const unsigned short* g, unsigned short* l) {
  __builtin_amdgcn_global_load_lds(
      (const __attribute__((address_space(1))) unsigned int*)(const void*)g,
      (__attribute__((address_space(3))) unsigned int*)(void*)l, 16, 0, 0);
}

// Stage a 64-row x 256-short tile (row stride kD) into S via global_load_lds.
// XOR swizzle: 16B-block at physical (row, c ^ (row&31)) holds logical block c.
// Lane L of wave w, instr i: p=w*8+i covers rows 2p,2p+1; slot p*64+L =
// (row, L&31) physical -> load logical c = (L&31)^(row&31). Global side stays
// inside each 512B row (perfectly coalesced); read side (lanes = distinct
// rows) hits 32 distinct 16B blocks = conflict-free without padding.
__device__ inline void stage_tile_async(const unsigned short* src,
                                        unsigned short* S, int w, int lane) {
  const int hi = lane >> 5, lo = lane & 31;
#pragma unroll
  for (int i = 0; i < 8; ++i) {
    const int p = w * 8 + i;
    const int rowl = p * 2 + hi;
    const int c = lo ^ (rowl & 31);
    async16(src + (size_t)rowl * kD + c * 8, S + p * 512);
  }
}
// Read one 16B MFMA fragment (logical shorts [kc*16+half*8 ..)) from the
// swizzled tile.
__device__ inline uint4 lds_frag(const unsigned short* S, int row, int kc, int half) {
  const int c = (kc * 2 + half) ^ (row & 31);
  return *reinterpret_cast<const uint4*>(S + row * 256 + c * 8);
}

// ---- Kernel 0: prep = weight transpose (blocks 0..127) + zero scratch ------
__global__ __launch_bounds__(256) void prep(const float* __restrict__ W0,
                                            const float* __restrict__ W1,
                                            unsigned short* __restrict__ T0,
                                            unsigned short* __restrict__ T1,
                                            unsigned* __restrict__ zeroBase,
                                            int zeroWords) {
  const int blk = blockIdx.x;
  if (blk < 128) {
    const float* W = (blk & 64) ? W1 : W0;
    unsigned short* WT = (blk & 64) ? T1 : T0;
    const int t = blk & 63;
    const int c0 = (t & 7) * 32, k0 = (t >> 3) * 32;
    __shared__ float tile[32][33];
    const int tx = threadIdx.x & 31, ty = threadIdx.x >> 5;
#pragma unroll
    for (int i = 0; i < 4; ++i)
      tile[ty + i * 8][tx] = W[(size_t)(k0 + ty + i * 8) * kD + c0 + tx];
    __syncthreads();
#pragma unroll
    for (int i = 0; i < 4; ++i)
      WT[(size_t)(c0 + ty + i * 8) * kD + k0 + tx] = f2bf_rne(tile[tx][ty + i * 8]);
  } else {
    for (int i = (blk - 128) * 256 + threadIdx.x; i < zeroWords; i += 32 * 256)
      zeroBase[i] = 0u;
  }
}

// ---- Kernel 1: Cb = bf16( bf16(X) @ WT^T ) + fused row norms ---------------
// r11 structure; WT tiles now staged via global_load_lds + swizzle (X keeps
// the padded VGPR-cast path -- fp32->bf16 conversion can't use async copy).
__global__ __launch_bounds__(256) void gemm_hyb(const float* __restrict__ Xv,
                                                const float* __restrict__ Xa,
                                                const unsigned short* __restrict__ WvT,
                                                const unsigned short* __restrict__ WaT,
                                                unsigned short* __restrict__ Cv,
                                                unsigned short* __restrict__ Ca,
                                                float* __restrict__ nv,
                                                float* __restrict__ na) {
  __shared__ unsigned short S[64 * kStr];   // 33792B; holds X(padded) then WT(swizzled)
  const int z = blockIdx.z;
  const float* X = z ? Xa : Xv;
  const unsigned short* WT = z ? WaT : WvT;
  unsigned short* Cb = z ? Ca : Cv;
  float* nrm = z ? na : nv;
  const int r0 = blockIdx.x * 64;
  const int cHalf = blockIdx.y;
  const int tid = threadIdx.x;
  const int w = tid >> 6, lane = tid & 63;
  const int wt = w & 1, wc = w >> 1;
  const int half = lane >> 5, ln = lane & 31;

  // stage X: 64 rows x 256 fp32, coalesced, cast inline (padded layout)
#pragma unroll
  for (int i = 0; i < 16; ++i) {
    const int idx = i * 256 + tid;
    const int row = idx >> 6, g = idx & 63;
    const float4 v = *reinterpret_cast<const float4*>(X + (size_t)(r0 + row) * kD + g * 4);
    ushort4 o;
    o.x = f2bf_rne(v.x); o.y = f2bf_rne(v.y); o.z = f2bf_rne(v.z); o.w = f2bf_rne(v.w);
    *reinterpret_cast<ushort4*>(S + row * kStr + g * 4) = o;
  }
  __syncthreads();
  uint4 afr[16];
#pragma unroll
  for (int kc = 0; kc < 16; ++kc)
    afr[kc] = *reinterpret_cast<const uint4*>(S + (wt * 32 + ln) * kStr + kc * 16 + half * 8);

  float ns[16];
#pragma unroll
  for (int r = 0; r < 16; ++r) ns[r] = 0.0f;

  for (int ct = 0; ct < 2; ++ct) {
    const int c0 = (cHalf * 2 + ct) * 64;
    __syncthreads();  // afr reads / prev MFMA fb reads done
    stage_tile_async(WT + (size_t)c0 * kD, S, w, lane);
    __syncthreads();  // drains vmcnt: async tile resident
    f32x16 acc;
#pragma unroll
    for (int i = 0; i < 16; ++i) acc[i] = 0.0f;
#pragma unroll
    for (int kc = 0; kc < 16; ++kc) {
      FragU fa, fb;
      fa.u4 = afr[kc];
      fb.u4 = lds_frag(S, wc * 32 + ln, kc, half);
      acc = __builtin_amdgcn_mfma_f32_32x32x16_bf16(fa.v, fb.v, acc, 0, 0, 0);
    }
    const int col = c0 + wc * 32 + ln;
#pragma unroll
    for (int r = 0; r < 16; ++r) {
      const int row = r0 + wt * 32 + (r & 3) + 8 * (r >> 2) + 4 * half;
      const unsigned short us = f2bf_rne(acc[r]);
      Cb[(size_t)row * kD + col] = us;
      const float f = bf2f(us);
      ns[r] += f * f;
    }
  }
#pragma unroll
  for (int r = 0; r < 16; ++r) {
    float v = ns[r];
#pragma unroll
    for (int off = 1; off < 32; off <<= 1) v += __shfl_xor(v, off, 64);
    if (ln == 0) {
      const int row = r0 + wt * 32 + (r & 3) + 8 * (r >> 2) + 4 * half;
      atomicAdd(nrm + row, v);
    }
  }
}

// ---- Kernel 2: distance keys, 128t x 256s, all staging via global_load_lds -
// r11 keys_v12 structure with async+swizzled staging (no VGPR round-trip, no
// ds_write, 32KB LDS). MFMA operand values identical to r11 -> selection
// bit-identical (sq<7744 == dist<88 guard, flush below 2^-126).
__global__ __launch_bounds__(256) void keys_v14(const unsigned short* __restrict__ vmb,
                                                const unsigned short* __restrict__ amb,
                                                const float* __restrict__ vn2,
                                                const float* __restrict__ an2,
                                                unsigned* __restrict__ colCount,
                                                uint2* __restrict__ colRecs,
                                                unsigned* __restrict__ ovCount,
                                                uint2* __restrict__ ovRecs) {
  __shared__ unsigned short S[64 * 256];   // 32KB, swizzled tiles
  const int b = blockIdx.z;
  const int t0 = blockIdx.x * 128;
  const int sr0 = blockIdx.y * 256;
  const int tid = threadIdx.x;
  const int w = tid >> 6, lane = tid & 63;
  const int half = lane >> 5, ln = lane & 31;

  // A: two 64-row vm halves staged async; waves (w>>1)==h read theirs
  uint4 afr[16];
#pragma unroll
  for (int h = 0; h < 2; ++h) {
    __syncthreads();
    stage_tile_async(vmb + ((size_t)b * kT + t0 + h * 64) * kD, S, w, lane);
    __syncthreads();
    if ((w >> 1) == h) {
#pragma unroll
      for (int kc = 0; kc < 16; ++kc)
        afr[kc] = lds_frag(S, (w & 1) * 32 + ln, kc, half);
    }
  }

  const float* v2p = vn2 + (size_t)b * kT + t0 + w * 32;

  for (int st = 0; st < 4; ++st) {
    const int s0 = sr0 + st * 64;
    __syncthreads();  // afr reads / prev MFMA fb reads done
    stage_tile_async(amb + ((size_t)b * kT + s0) * kD, S, w, lane);
    __syncthreads();  // drains vmcnt: am tile resident
    f32x16 acc[2];
#pragma unroll
    for (int j = 0; j < 2; ++j)
#pragma unroll
      for (int i = 0; i < 16; ++i) acc[j][i] = 0.0f;
#pragma unroll
    for (int kc = 0; kc < 16; ++kc) {
      FragU fa; fa.u4 = afr[kc];
#pragma unroll
      for (int ss = 0; ss < 2; ++ss) {
        FragU fb;
        fb.u4 = lds_frag(S, ss * 32 + ln, kc, half);
        acc[ss] = __builtin_amdgcn_mfma_f32_32x32x16_bf16(fa.v, fb.v, acc[ss], 0, 0, 0);
      }
    }
    // epilogue: col(s)=lane&31, row(t)=(reg&3)+8*(reg>>2)+4*half
#pragma unroll
    for (int ss = 0; ss < 2; ++ss) {
      const int s = s0 + ss * 32 + ln;
      const float a2 = an2[(size_t)b * kT + s];
      const int c = (b << 11) | s;
#pragma unroll
      for (int g = 0; g < 4; ++g) {
        const float4 v2 = *reinterpret_cast<const float4*>(v2p + g * 8 + half * 4);
        const float v2a[4] = {v2.x, v2.y, v2.z, v2.w};
#pragma unroll
        for (int q = 0; q < 4; ++q) {
          const float raw = v2a[q] + a2 - 2.0f * acc[ss][4 * g + q];
          if (raw < 7744.0f) {  // == dist < 88; ~3e-4 of entries
            const float dist = sqrtf(fmaxf(raw, 0.0f));
            const float e = expf(-dist);
            if (e >= kMinNormalF) {
              const int t = t0 + w * 32 + g * 8 + half * 4 + q;
              const unsigned slot = atomicAdd(&colCount[c], 1u);
              if (slot < (unsigned)kColCap) {
                colRecs[(size_t)c * kColCap + slot] = make_uint2(__float_as_uint(e), (unsigned)t);
              } else {
                const unsigned pos = ((unsigned)b << 22) | ((unsigned)s << 11) | (unsigned)t;
                const unsigned oi = atomicAdd(ovCount, 1u);
                if (oi < (unsigned)kOvCap) ovRecs[oi] = make_uint2(__float_as_uint(e), pos);
              }
            }
          }
        }
      }
    }
  }
}

// ---- Kernel 3: fused finalize + gather (HW-validated in r13's mega) --------
// Block u = (bj, ch): 32 threads recompute top-8 for the 32 columns of this
// s-chunk straight from the per-column buckets (mean 0.55 records), pick the
// j-th index, then all 256 threads gather-partial into pv/pa.
__global__ __launch_bounds__(256) void gather_fused(const float* __restrict__ visual,
                                                    const float* __restrict__ audio,
                                                    const unsigned* __restrict__ colCount,
                                                    const uint2* __restrict__ colRecs,
                                                    const unsigned* __restrict__ ovCount,
                                                    const uint2* __restrict__ ovRecs,
                                                    float* __restrict__ pv,
                                                    float* __restrict__ pa) {
  __shared__ int sIdx[32];
  const int u = blockIdx.x;              // 4096 = 64 bj x 64 chunks
  const int bj = u >> 6, ch = u & 63;
  const int b = bj >> 3, j = bj & 7;
  const int tid = threadIdx.x;
  if (tid < 32) {
    const int s = ch * 32 + tid;
    const int c = (b << 11) | s;
    unsigned K[8]; int T[8];
#pragma unroll
    for (int i = 0; i < 8; ++i) { K[i] = 0u; T[i] = 0x7FFFFFFF; }
    const int cnt = (int)colCount[c];
    const int m = min(cnt, kColCap);
    for (int i = 0; i < m; ++i) {
      const uint2 r = colRecs[(size_t)c * kColCap + i];
      const unsigned kx = r.x; const int tx = (int)r.y;
      if (kx > K[7] || (kx == K[7] && tx < T[7])) {
        K[7] = kx; T[7] = tx;
#pragma unroll
        for (int q = 7; q >= 1; --q) {
          const bool sw = (K[q] > K[q - 1]) || (K[q] == K[q - 1] && T[q] < T[q - 1]);
          if (sw) {
            const unsigned tk = K[q]; K[q] = K[q - 1]; K[q - 1] = tk;
            const int tt = T[q];      T[q] = T[q - 1]; T[q - 1] = tt;
          }
        }
      }
    }
    if (cnt > kColCap) {  // correctness fallback; normally never taken
      int n = (int)*ovCount;
      if (n > kOvCap) n = kOvCap;
      for (int i = 0; i < n; ++i) {
        const uint2 r = ovRecs[i];
        if ((int)(r.y >> 11) == c) {
          const unsigned kx = r.x; const int tx = (int)(r.y & 2047u);
          if (kx > K[7] || (kx == K[7] && tx < T[7])) {
            K[7] = kx; T[7] = tx;
#pragma unroll
            for (int q = 7; q >= 1; --q) {
              const bool sw = (K[q] > K[q - 1]) || (K[q] == K[q - 1] && T[q] < T[q - 1]);
              if (sw) {
                const unsigned tk = K[q]; K[q] = K[q - 1]; K[q - 1] = tk;
                const int tt = T[q];      T[q] = T[q - 1]; T[q - 1] = tt;
              }
            }
          }
        }
      }
    }
    int mcnt = 0;
#pragma unroll
    for (int i = 0; i < 8; ++i) if (K[i] > 0u) mcnt++;
    int outv[8];
#pragma unroll
    for (int i = 0; i < 8; ++i) outv[i] = T[i];
    int cand = 0;
    for (int r = mcnt; r < 8; ++r) {
      bool taken = true;
      while (taken) {
        taken = false;
#pragma unroll
        for (int q = 0; q < 8; ++q)
          if (q < mcnt && T[q] == cand) taken = true;
        if (taken) cand++;
      }
      outv[r] = cand++;
    }
    sIdx[tid] = outv[j];
  }
  __syncthreads();
  float accV = 0.f, accA = 0.f;
  for (int i = 0; i < 32; ++i) {
    const int t = sIdx[i];
    const size_t base = ((size_t)b * kT + t) * kD + tid;
    accV += visual[base];
    accA += audio[base];
  }
  pv[(size_t)u * kD + tid] = accV;
  pa[(size_t)u * kD + tid] = accA;
}

// ---- Kernel 4: reduce partials, divide by Ta, write both outputs -----------
__global__ __launch_bounds__(256) void reduce_kernel(const float* __restrict__ pv,
                                                     const float* __restrict__ pa,
                                                     float* __restrict__ out) {
  const int bj = blockIdx.x;
  const int d = threadIdx.x;
  float sV = 0.f, sA = 0.f;
#pragma unroll 8
  for (int ch = 0; ch < 64; ++ch) {
    sV += pv[((size_t)bj * 64 + ch) * kD + d];
    sA += pa[((size_t)bj * 64 + ch) * kD + d];
  }
  out[(size_t)bj * kD + d] = sV * (1.0f / kT);
  out[(size_t)kB * kK * kD + (size_t)bj * kD + d] = sA * (1.0f / kT);
}

extern "C" void kernel_launch(void* const* d_in, const int* in_sizes, int n_in,
                              void* d_out, int out_size, void* d_ws, size_t ws_size,
                              hipStream_t stream) {
  (void)in_sizes; (void)n_in; (void)out_size; (void)ws_size;
  const float* visual = (const float*)d_in[0];
  const float* audio  = (const float*)d_in[1];
  const float* Wv     = (const float*)d_in[2];
  const float* Wa     = (const float*)d_in[3];
  float* out = (float*)d_out;

  // workspace layout (~35 MB). [vn2|an2|colCount|ovCount] contiguous: zeroed by prep.
  char* ws = (char*)d_ws;
  unsigned short* WvT = (unsigned short*)ws;                // kD*kD bf16 128KB
  unsigned short* WaT = WvT + (size_t)kD * kD;
  unsigned short* vmb = WaT + (size_t)kD * kD;              // kM*kD bf16  8MB
  unsigned short* amb = vmb + (size_t)kM * kD;              // 8MB
  float* vn2 = (float*)(amb + (size_t)kM * kD);             // kM f32 (zeroed)
  float* an2 = vn2 + kM;                                    // kM f32 (zeroed)
  unsigned* colCount = (unsigned*)(an2 + kM);               // kNC u32 (zeroed)
  unsigned* ovCount  = colCount + kNC;                      // 1 u32 +7 pad (zeroed)
  uint2* colRecs = (uint2*)(ovCount + 8);                   // kNC*kColCap uint2 8MB
  uint2* ovRecs  = colRecs + (size_t)kNC * kColCap;         // kOvCap uint2 1MB
  float* pv = (float*)(ovRecs + kOvCap);                    // 4096*256 f32 4MB
  float* pa = pv + (size_t)4096 * kD;                       // 4MB
  const int zeroWords = 2 * kM + kNC + 8;

  prep<<<dim3(160), 256, 0, stream>>>(Wv, Wa, WvT, WaT, (unsigned*)vn2, zeroWords);
  gemm_hyb<<<dim3(kM / 64, 2, 2), 256, 0, stream>>>(visual, audio, WvT, WaT,
                                                    vmb, amb, vn2, an2);
  keys_v14<<<dim3(kT / 128, kT / 256, kB), 256, 0, stream>>>(vmb, amb, vn2, an2,
                                                             colCount, colRecs, ovCount, ovRecs);
  gather_fused<<<dim3(4096), 256, 0, stream>>>(visual, audio, colCount, colRecs,
                                               ovCount, ovRecs, pv, pa);
  reduce_kernel<<<dim3(kB * kK), 256, 0, stream>>>(pv, pa, out);
}